// Round 19
// baseline (83.356 us; speedup 1.0000x reference)
//
#include <hip/hip_runtime.h>
#include <hip/hip_bf16.h>

typedef __hip_bfloat16 bf16;
typedef float in_t;
typedef float out_t;
typedef __attribute__((ext_vector_type(8))) short short8;   // 8 bf16 MFMA operand
typedef __attribute__((ext_vector_type(4))) float f32x4;    // MFMA accumulator

#define CH    64
#define CIN1  32
#define CIN2  64
#define S1    186624   // 36*72*72
#define W1    5184     // 72*72
#define S2    23328    // 18*36*36
#define W2    1296     // 36*36
#define BSTR  104      // patch/operand lds bf16 row stride (b128-aligned, 2-way banks)
#define OSTR  136      // proj_x output tile ushort stride
#define YSTR  68       // proj_y output tile ushort stride
#define HWSTR 76       // pool LDS row stride
#define INV_NZ (1.0f/(288.0f + 1e-5f))

#define NB_PL 2304     // pool blocks (half-planes)
#define NB_PX 1458     // proj_x blocks
#define NB_PY 365      // proj_y blocks (4 wave-tiles each)
#define NBT   (NB_PL + NB_PX + NB_PY)   // 4127
#define NBR   (NBT - NB_PL)             // 1823

static __device__ __forceinline__ unsigned short f2bu(float f) {
    bf16 h = __float2bfloat16(f);
    unsigned short u;
    __builtin_memcpy(&u, &h, 2);
    return u;
}

// ---- fused stage 1, Bresenham-interleaved: pool | proj_x | proj_y
__global__ __launch_bounds__(256) void k_stage1(
    const in_t* __restrict__ x, const in_t* __restrict__ wi, const in_t* __restrict__ bi,
    bf16* __restrict__ xq,
    const in_t* __restrict__ y, const in_t* __restrict__ wf, const in_t* __restrict__ bf,
    unsigned short* __restrict__ yk,
    const in_t* __restrict__ z, unsigned short* __restrict__ xd)
{
    __shared__ __align__(16) char smem[17408];
    int t = threadIdx.x;
    long long i = blockIdx.x;

    long long pb = (i*NB_PL)/NBT;
    bool is_pool = ((i+1)*NB_PL)/NBT > pb;
    long long r  = i - pb;
    long long yb = (r*NB_PY)/NBR;
    bool is_py   = !is_pool && (((r+1)*NB_PY)/NBR > yb);

    if (is_pool) {
        int bid = (int)pb;
        float* dsum = reinterpret_cast<float*>(smem);
        int c  = bid / 36;
        int rr = bid - c*36;
        int od = rr >> 1, half = rr & 1;
        int hbase = half ? 35 : 0;
        int nrows = half ? 37 : 36;
        int oh0   = half ? 18 : 0;
        int dlo = od ? 2*od - 1 : 0;
        int nd  = od ? 3 : 2;
        const float* zb = z + ((size_t)c*36 + dlo)*W1;
        for (int ii = t; ii < nrows*18; ii += 256) {
            int rw = ii / 18, q = ii - (ii/18)*18;
            int off = (hbase + rw)*18 + q;
            const float4* p0 = reinterpret_cast<const float4*>(zb);
            float4 a = p0[off], b = p0[1296 + off];
            float4 s;
            if (nd == 3) {
                float4 e = p0[2592 + off];
                s = (float4){ a.x+b.x+e.x, a.y+b.y+e.y, a.z+b.z+e.z, a.w+b.w+e.w };
            } else {
                s = (float4){ a.x+b.x, a.y+b.y, a.z+b.z, a.w+b.w };
            }
            *reinterpret_cast<float4*>(&dsum[rw*HWSTR + q*4]) = s;
        }
        __syncthreads();
        float icd = (nd == 3) ? (1.f/3.f) : 0.5f;
        unsigned short* xdp = xd + (size_t)c*S2 + (size_t)od*W2 + oh0*36;
        for (int idx = t; idx < 648; idx += 256) {
            int ohl = idx / 36, ow = idx - (idx/36)*36;
            int oh = oh0 + ohl;
            int h0 = oh ? 2*oh-1 : 0, h1 = 2*oh+1;
            int w0 = ow ? 2*ow-1 : 0, w1 = 2*ow+1;
            float s = 0.f;
            for (int h = h0; h <= h1; ++h) {
                int lr = h - hbase;
                for (int w = w0; w <= w1; ++w)
                    s += dsum[lr*HWSTR + w];
            }
            float ich = (h1 - h0) == 1 ? 0.5f : (1.f/3.f);
            float icw = (w1 - w0) == 1 ? 0.5f : (1.f/3.f);
            xdp[idx] = f2bu(s * icd * ich * icw);
        }
    } else if (!is_py) {
        int gs0 = (int)(r - yb)*128;
        int l = t & 63, wv = t >> 6;
        int lcol = l & 15, loct = l >> 4;

        ushort4 rr4[2][4];
        #pragma unroll
        for (int mt = 0; mt < 2; ++mt) {
            int scol = gs0 + (wv*2 + mt)*16 + lcol;
            union { short8 v; unsigned short u[8]; } af;
            #pragma unroll
            for (int j = 0; j < 8; ++j)
                af.u[j] = f2bu(x[(size_t)(loct*8 + j)*S1 + scol]);
            #pragma unroll
            for (int og = 0; og < 4; ++og) {
                int o = og*16 + lcol;
                union { short8 v; unsigned short u[8]; } wfr;
                float4 a  = *reinterpret_cast<const float4*>(&wi[o*CIN1 + loct*8]);
                float4 bq = *reinterpret_cast<const float4*>(&wi[o*CIN1 + loct*8 + 4]);
                wfr.u[0]=f2bu(a.x);  wfr.u[1]=f2bu(a.y);
                wfr.u[2]=f2bu(a.z);  wfr.u[3]=f2bu(a.w);
                wfr.u[4]=f2bu(bq.x); wfr.u[5]=f2bu(bq.y);
                wfr.u[6]=f2bu(bq.z); wfr.u[7]=f2bu(bq.w);
                float bo = bi[o];
                f32x4 d = { bo, bo, bo, bo };
                d = __builtin_amdgcn_mfma_f32_16x16x32_bf16(af.v, wfr.v, d, 0, 0, 0);
                rr4[mt][og] = (ushort4){ f2bu(d[0]), f2bu(d[1]), f2bu(d[2]), f2bu(d[3]) };
            }
        }
        unsigned short* ot = reinterpret_cast<unsigned short*>(smem);  // 64 x OSTR
        #pragma unroll
        for (int mt = 0; mt < 2; ++mt)
            #pragma unroll
            for (int og = 0; og < 4; ++og)
                *reinterpret_cast<ushort4*>(
                    &ot[(og*16 + lcol)*OSTR + wv*32 + mt*16 + loct*4]) = rr4[mt][og];
        __syncthreads();
        #pragma unroll
        for (int j = 0; j < 4; ++j) {
            int row = wv*16 + j*4 + (l >> 4);
            int c8  = l & 15;
            uint4 v = *reinterpret_cast<const uint4*>(&ot[row*OSTR + c8*8]);
            *reinterpret_cast<uint4*>(
                (unsigned short*)xq + (size_t)row*S1 + gs0 + c8*8) = v;
        }
    } else {
        int pyb   = (int)yb;
        int sblk0 = pyb*64;
        int wv = t >> 6, l = t & 63;
        int lcol = l & 15, loct = l >> 4;
        int tile = pyb*4 + wv;
        unsigned short* ot = reinterpret_cast<unsigned short*>(smem);   // 64 x YSTR
        if (tile < 1458) {
            int s0 = tile*16;
            union { short8 v; unsigned short u[8]; } af[2];
            #pragma unroll
            for (int kk = 0; kk < 2; ++kk)
                #pragma unroll
                for (int j = 0; j < 8; ++j)
                    af[kk].u[j] = f2bu(y[(size_t)(kk*32 + loct*8 + j)*S2 + s0 + lcol]);
            #pragma unroll
            for (int og = 0; og < 4; ++og) {
                int o = og*16 + lcol;
                union { short8 v; unsigned short u[8]; } wfr[2];
                #pragma unroll
                for (int kk = 0; kk < 2; ++kk) {
                    float4 a  = *reinterpret_cast<const float4*>(&wf[o*CIN2 + kk*32 + loct*8]);
                    float4 bq = *reinterpret_cast<const float4*>(&wf[o*CIN2 + kk*32 + loct*8 + 4]);
                    wfr[kk].u[0]=f2bu(a.x);  wfr[kk].u[1]=f2bu(a.y);
                    wfr[kk].u[2]=f2bu(a.z);  wfr[kk].u[3]=f2bu(a.w);
                    wfr[kk].u[4]=f2bu(bq.x); wfr[kk].u[5]=f2bu(bq.y);
                    wfr[kk].u[6]=f2bu(bq.z); wfr[kk].u[7]=f2bu(bq.w);
                }
                float bo = bf[o];
                f32x4 d = { bo, bo, bo, bo };
                d = __builtin_amdgcn_mfma_f32_16x16x32_bf16(af[0].v, wfr[0].v, d, 0, 0, 0);
                d = __builtin_amdgcn_mfma_f32_16x16x32_bf16(af[1].v, wfr[1].v, d, 0, 0, 0);
                ushort4 r4 = { f2bu(d[0]), f2bu(d[1]), f2bu(d[2]), f2bu(d[3]) };
                *reinterpret_cast<ushort4*>(&ot[(og*16 + lcol)*YSTR + wv*16 + loct*4]) = r4;
            }
        }
        __syncthreads();
        #pragma unroll
        for (int j = 0; j < 4; ++j) {
            int row = wv*16 + j*4 + (l >> 4);
            int c4  = l & 15;
            int s   = sblk0 + c4*4;
            if (s < S2) {
                ushort4 v = *reinterpret_cast<const ushort4*>(&ot[row*YSTR + c4*4]);
                *reinterpret_cast<ushort4*>(&yk[(size_t)row*S2 + s]) = v;
            }
        }
    }
}

// ---- fused corr: each block computes its channel's M(96x96) in LDS (redundant x12),
// then C(96x192) = Ml x Uxq^T + fold + LeakyReLU + residual.
// grid = 64c * 4ph * 3ck = 768 blocks, 256 threads; LDS 59904B -> 2 blocks/CU
__global__ __launch_bounds__(256, 2) void k_corr(
    const unsigned short* __restrict__ xd, const unsigned short* __restrict__ yk,
    const bf16* __restrict__ xq, const in_t* __restrict__ z, out_t* __restrict__ out)
{
    __shared__ __align__(16) char smem[59904];
    unsigned short* Al = reinterpret_cast<unsigned short*>(smem);            // 96*BSTR
    unsigned short* Bl = reinterpret_cast<unsigned short*>(smem) + 96*BSTR;  // 96*BSTR
    unsigned short* Ml = reinterpret_cast<unsigned short*>(smem) + 2*96*BSTR;// 96*BSTR
    unsigned short* Pl = reinterpret_cast<unsigned short*>(smem);            // reuse Al/Bl
    int bid = blockIdx.x;
    int c   = bid / 12;
    int rem = bid - c*12;
    int ph  = rem / 3;
    int ck  = rem - ph*3;
    int colbase = ck*1728;
    int t = threadIdx.x;
    int wv = t >> 6, l = t & 63;
    int lcol = l & 15, lhi = l >> 4;

    // ===== phase 1: M_c = Uxd_pad(96x288) x Uy_pad^T (k_M formulation, output to LDS)
    int wr = wv >> 1, wc = wv & 1;
    for (int idx = t; idx < 15*BSTR; idx += 256) {
        Al[81*BSTR + idx] = 0;
        Bl[81*BSTR + idx] = 0;
    }
    f32x4 macc[3][3];
    #pragma unroll
    for (int a = 0; a < 3; ++a)
        #pragma unroll
        for (int b = 0; b < 3; ++b)
            macc[a][b] = (f32x4){0.f,0.f,0.f,0.f};

    const unsigned short* xc = xd + (size_t)c*S2;
    const unsigned short* yc = yk + (size_t)c*S2;
    for (int q = 0; q < 3; ++q) {
        __syncthreads();
        for (int idx = t; idx < 1944; idx += 256) {
            int r18 = idx / 108, u4 = idx - r18*108;
            int srcoff = r18*W2 + q*432 + u4*4;
            ushort4 va = *reinterpret_cast<const ushort4*>(xc + srcoff);
            ushort4 vb = *reinterpret_cast<const ushort4*>(yc + srcoff);
            int ph2 = r18 / 9, i2 = r18 - ph2*9;
            unsigned short ua[4] = {va.x, va.y, va.z, va.w};
            unsigned short ub[4] = {vb.x, vb.y, vb.z, vb.w};
            #pragma unroll
            for (int j = 0; j < 4; ++j) {
                int cc  = u4*4 + j;
                int pw2 = cc / 9, j2 = cc - pw2*9;
                int row = i2*9 + j2;
                int mp  = pw2*2 + ph2;
                Al[row*BSTR + mp] = ua[j];
                Bl[row*BSTR + mp] = ub[j];
            }
        }
        __syncthreads();
        #pragma unroll
        for (int kk = 0; kk < 3; ++kk) {
            short8 afr[3], bfr[3];
            #pragma unroll
            for (int a = 0; a < 3; ++a)
                afr[a] = *reinterpret_cast<const short8*>(
                    &Al[(wr*48 + a*16 + lcol)*BSTR + kk*32 + lhi*8]);
            #pragma unroll
            for (int b = 0; b < 3; ++b)
                bfr[b] = *reinterpret_cast<const short8*>(
                    &Bl[(wc*48 + b*16 + lcol)*BSTR + kk*32 + lhi*8]);
            #pragma unroll
            for (int a = 0; a < 3; ++a)
                #pragma unroll
                for (int b = 0; b < 3; ++b)
                    macc[a][b] = __builtin_amdgcn_mfma_f32_16x16x32_bf16(
                        afr[a], bfr[b], macc[a][b], 0, 0, 0);
        }
    }
    #pragma unroll
    for (int a = 0; a < 3; ++a)
        #pragma unroll
        for (int b = 0; b < 3; ++b)
            #pragma unroll
            for (int rr = 0; rr < 4; ++rr) {
                int k1 = wr*48 + a*16 + lhi*4 + rr;
                int k2 = wc*48 + b*16 + lcol;
                Ml[k1*BSTR + k2] = f2bu(macc[a][b][rr]);
            }
    __syncthreads();   // Ml complete; Al/Bl dead -> reuse as Pl

    // ===== phase 2: stage Uxq patches, C = Ml x Uxq^T, epilogue
    for (int idx = t; idx < 192*15; idx += 256) {
        int r = idx/15;
        Pl[r*BSTR + 81 + (idx - r*15)] = 0;
    }
    const unsigned short* xqu =
        (const unsigned short*)(xq + (size_t)c*S1 + (size_t)(ph*9)*W1 + colbase);
    for (int idx = t; idx < 3888; idx += 256) {
        int i2 = idx / 432, v4 = idx - i2*432;
        ushort4 vv = *reinterpret_cast<const ushort4*>(xqu + (size_t)i2*W1 + v4*4);
        int col = v4*4;
        unsigned short uu[4] = {vv.x, vv.y, vv.z, vv.w};
        #pragma unroll
        for (int j = 0; j < 4; ++j) {
            int cc = col + j;
            int p = cc/9, j2 = cc - p*9;
            Pl[p*BSTR + i2*9 + j2] = uu[j];
        }
    }
    __syncthreads();

    int lrow = l & 15;

    short8 bfr[3][3];
    #pragma unroll
    for (int ntl = 0; ntl < 3; ++ntl) {
        int n = (wv*3 + ntl)*16 + lrow;
        #pragma unroll
        for (int kk = 0; kk < 3; ++kk)
            bfr[ntl][kk] = *reinterpret_cast<const short8*>(&Pl[n*BSTR + kk*32 + lhi*8]);
    }

    f32x4 acc[6][3];
    #pragma unroll
    for (int mt = 0; mt < 6; ++mt)
        #pragma unroll
        for (int ntl = 0; ntl < 3; ++ntl)
            acc[mt][ntl] = (f32x4){0.f,0.f,0.f,0.f};

    #pragma unroll
    for (int mt = 0; mt < 6; ++mt) {
        short8 afr[3];
        #pragma unroll
        for (int kk = 0; kk < 3; ++kk)
            afr[kk] = *reinterpret_cast<const short8*>(
                &Ml[(mt*16 + lrow)*BSTR + kk*32 + lhi*8]);
        #pragma unroll
        for (int ntl = 0; ntl < 3; ++ntl) {
            f32x4 d = acc[mt][ntl];
            #pragma unroll
            for (int kk = 0; kk < 3; ++kk)
                d = __builtin_amdgcn_mfma_f32_16x16x32_bf16(afr[kk], bfr[ntl][kk], d, 0, 0, 0);
            acc[mt][ntl] = d;
        }
    }
    __syncthreads();

    float* stage = reinterpret_cast<float*>(Pl);   // 9 x 864 fp32 = 31104B <= 39936
    #pragma unroll
    for (int pass = 0; pass < 2; ++pass) {
        if ((wv >> 1) == pass) {
            #pragma unroll
            for (int mt = 0; mt < 6; ++mt)
                #pragma unroll
                for (int ntl = 0; ntl < 3; ++ntl) {
                    int n = (wv*3 + ntl)*16 + lrow - pass*96;
                    #pragma unroll
                    for (int r = 0; r < 4; ++r) {
                        int m = mt*16 + lhi*4 + r;
                        if (m <= 80) {
                            int i = m/9, j = m - 9*i;
                            stage[i*864 + n*9 + j] = acc[mt][ntl][r];
                        }
                    }
                }
        }
        __syncthreads();
        for (int idx = t; idx < 1944; idx += 256) {
            int i = idx/216, c4 = idx - i*216;
            float4 sv = *reinterpret_cast<const float4*>(&stage[i*864 + c4*4]);
            int ga = c*S1 + (ph*9 + i)*W1 + colbase + pass*864 + c4*4;
            float4 dv = *reinterpret_cast<const float4*>(&z[ga]);
            float4 ov;
            float cr;
            cr = sv.x*INV_NZ; ov.x = dv.x + (cr > 0.f ? cr : 0.2f*cr)*dv.x;
            cr = sv.y*INV_NZ; ov.y = dv.y + (cr > 0.f ? cr : 0.2f*cr)*dv.y;
            cr = sv.z*INV_NZ; ov.z = dv.z + (cr > 0.f ? cr : 0.2f*cr)*dv.z;
            cr = sv.w*INV_NZ; ov.w = dv.w + (cr > 0.f ? cr : 0.2f*cr)*dv.w;
            *reinterpret_cast<float4*>(&out[ga]) = ov;
        }
        __syncthreads();
    }
}

extern "C" void kernel_launch(void* const* d_in, const int* in_sizes, int n_in,
                              void* d_out, int out_size, void* d_ws, size_t ws_size,
                              hipStream_t stream)
{
    (void)in_sizes; (void)n_in; (void)out_size; (void)ws_size;
    const in_t* x     = (const in_t*)d_in[0];
    const in_t* y     = (const in_t*)d_in[1];
    const in_t* z     = (const in_t*)d_in[2];
    const in_t* w_img = (const in_t*)d_in[3];
    const in_t* b_img = (const in_t*)d_in[4];
    const in_t* w_fea = (const in_t*)d_in[5];
    const in_t* b_fea = (const in_t*)d_in[6];
    out_t* out = (out_t*)d_out;

    char* ws = (char*)d_ws;
    bf16*           xq = (bf16*)          (ws + 0);          // 23,887,872
    unsigned short* yk = (unsigned short*)(ws + 23887872);   // 2,985,984
    unsigned short* xd = (unsigned short*)(ws + 26873856);   // 2,985,984

    hipLaunchKernelGGL(k_stage1, dim3(NBT), dim3(256), 0, stream,
                       x, w_img, b_img, xq, y, w_fea, b_fea, yk, z, xd);
    hipLaunchKernelGGL(k_corr,   dim3(768), dim3(256), 0, stream, xd, yk, xq, z, out);
}

// Round 21
// 66.232 us; speedup vs baseline: 1.2585x; 1.2585x over previous
//
#include <hip/hip_runtime.h>
#include <hip/hip_bf16.h>

typedef __hip_bfloat16 bf16;
typedef float in_t;
typedef float out_t;
typedef __attribute__((ext_vector_type(8))) short short8;   // 8 bf16 MFMA operand
typedef __attribute__((ext_vector_type(4))) float f32x4;    // MFMA accumulator

#define CH    64
#define CIN1  32
#define CIN2  64
#define S1    186624   // 36*72*72
#define W1    5184     // 72*72
#define S2    23328    // 18*36*36
#define W2    1296     // 36*36
#define BSTR  104      // k_corr patch lds bf16 row stride
#define ASTR  104      // k_M operand lds bf16 row stride (b128-aligned)
#define OSTR  136      // proj_x output tile ushort stride
#define YSTR  68       // proj_y output tile ushort stride
#define HWSTR 76       // pool LDS row stride
#define INV_NZ (1.0f/(288.0f + 1e-5f))

#define NB_PL 2304     // pool blocks (half-planes)
#define NB_PX 1458     // proj_x blocks
#define NB_PY 365      // proj_y blocks (4 wave-tiles each)
#define NBT   (NB_PL + NB_PX + NB_PY)   // 4127
#define NBR   (NBT - NB_PL)             // 1823

static __device__ __forceinline__ unsigned short f2bu(float f) {
    bf16 h = __float2bfloat16(f);
    unsigned short u;
    __builtin_memcpy(&u, &h, 2);
    return u;
}

// ---- fused stage 1, Bresenham-interleaved: pool | proj_x | proj_y mixed across dispatch
__global__ __launch_bounds__(256) void k_stage1(
    const in_t* __restrict__ x, const in_t* __restrict__ wi, const in_t* __restrict__ bi,
    bf16* __restrict__ xq,
    const in_t* __restrict__ y, const in_t* __restrict__ wf, const in_t* __restrict__ bf,
    unsigned short* __restrict__ yk,
    const in_t* __restrict__ z, unsigned short* __restrict__ xd)
{
    __shared__ __align__(16) char smem[17408];
    int t = threadIdx.x;
    long long i = blockIdx.x;

    long long pb = (i*NB_PL)/NBT;
    bool is_pool = ((i+1)*NB_PL)/NBT > pb;
    long long r  = i - pb;
    long long yb = (r*NB_PY)/NBR;
    bool is_py   = !is_pool && (((r+1)*NB_PY)/NBR > yb);

    if (is_pool) {
        int bid = (int)pb;
        float* dsum = reinterpret_cast<float*>(smem);
        int c  = bid / 36;
        int rr = bid - c*36;
        int od = rr >> 1, half = rr & 1;
        int hbase = half ? 35 : 0;
        int nrows = half ? 37 : 36;
        int oh0   = half ? 18 : 0;
        int dlo = od ? 2*od - 1 : 0;
        int nd  = od ? 3 : 2;
        const float* zb = z + ((size_t)c*36 + dlo)*W1;
        for (int ii = t; ii < nrows*18; ii += 256) {
            int rw = ii / 18, q = ii - (ii/18)*18;
            int off = (hbase + rw)*18 + q;
            const float4* p0 = reinterpret_cast<const float4*>(zb);
            float4 a = p0[off], b = p0[1296 + off];
            float4 s;
            if (nd == 3) {
                float4 e = p0[2592 + off];
                s = (float4){ a.x+b.x+e.x, a.y+b.y+e.y, a.z+b.z+e.z, a.w+b.w+e.w };
            } else {
                s = (float4){ a.x+b.x, a.y+b.y, a.z+b.z, a.w+b.w };
            }
            *reinterpret_cast<float4*>(&dsum[rw*HWSTR + q*4]) = s;
        }
        __syncthreads();
        float icd = (nd == 3) ? (1.f/3.f) : 0.5f;
        unsigned short* xdp = xd + (size_t)c*S2 + (size_t)od*W2 + oh0*36;
        for (int idx = t; idx < 648; idx += 256) {
            int ohl = idx / 36, ow = idx - (idx/36)*36;
            int oh = oh0 + ohl;
            int h0 = oh ? 2*oh-1 : 0, h1 = 2*oh+1;
            int w0 = ow ? 2*ow-1 : 0, w1 = 2*ow+1;
            float s = 0.f;
            for (int h = h0; h <= h1; ++h) {
                int lr = h - hbase;
                for (int w = w0; w <= w1; ++w)
                    s += dsum[lr*HWSTR + w];
            }
            float ich = (h1 - h0) == 1 ? 0.5f : (1.f/3.f);
            float icw = (w1 - w0) == 1 ? 0.5f : (1.f/3.f);
            xdp[idx] = f2bu(s * icd * ich * icw);
        }
    } else if (!is_py) {
        // ---- proj_x: xq(64,S1) = Wi(64,32) x x(32,S1) + bi, bf16 out
        int gs0 = (int)(r - yb)*128;
        int l = t & 63, wv = t >> 6;
        int lcol = l & 15, loct = l >> 4;

        ushort4 rr4[2][4];
        #pragma unroll
        for (int mt = 0; mt < 2; ++mt) {
            int scol = gs0 + (wv*2 + mt)*16 + lcol;
            union { short8 v; unsigned short u[8]; } af;
            #pragma unroll
            for (int j = 0; j < 8; ++j)
                af.u[j] = f2bu(x[(size_t)(loct*8 + j)*S1 + scol]);
            #pragma unroll
            for (int og = 0; og < 4; ++og) {
                int o = og*16 + lcol;
                union { short8 v; unsigned short u[8]; } wfr;
                float4 a  = *reinterpret_cast<const float4*>(&wi[o*CIN1 + loct*8]);
                float4 bq = *reinterpret_cast<const float4*>(&wi[o*CIN1 + loct*8 + 4]);
                wfr.u[0]=f2bu(a.x);  wfr.u[1]=f2bu(a.y);
                wfr.u[2]=f2bu(a.z);  wfr.u[3]=f2bu(a.w);
                wfr.u[4]=f2bu(bq.x); wfr.u[5]=f2bu(bq.y);
                wfr.u[6]=f2bu(bq.z); wfr.u[7]=f2bu(bq.w);
                float bo = bi[o];
                f32x4 d = { bo, bo, bo, bo };
                d = __builtin_amdgcn_mfma_f32_16x16x32_bf16(af.v, wfr.v, d, 0, 0, 0);
                rr4[mt][og] = (ushort4){ f2bu(d[0]), f2bu(d[1]), f2bu(d[2]), f2bu(d[3]) };
            }
        }
        unsigned short* ot = reinterpret_cast<unsigned short*>(smem);  // 64 x OSTR
        #pragma unroll
        for (int mt = 0; mt < 2; ++mt)
            #pragma unroll
            for (int og = 0; og < 4; ++og)
                *reinterpret_cast<ushort4*>(
                    &ot[(og*16 + lcol)*OSTR + wv*32 + mt*16 + loct*4]) = rr4[mt][og];
        __syncthreads();
        #pragma unroll
        for (int j = 0; j < 4; ++j) {
            int row = wv*16 + j*4 + (l >> 4);
            int c8  = l & 15;
            uint4 v = *reinterpret_cast<const uint4*>(&ot[row*OSTR + c8*8]);
            *reinterpret_cast<uint4*>(
                (unsigned short*)xq + (size_t)row*S1 + gs0 + c8*8) = v;
        }
    } else {
        // ---- proj_y: yk(64,S2) = Wf(64,64) x y(64,S2) + bf, bf16 out
        int pyb   = (int)yb;
        int sblk0 = pyb*64;
        int wv = t >> 6, l = t & 63;
        int lcol = l & 15, loct = l >> 4;
        int tile = pyb*4 + wv;
        unsigned short* ot = reinterpret_cast<unsigned short*>(smem);   // 64 x YSTR
        if (tile < 1458) {
            int s0 = tile*16;
            union { short8 v; unsigned short u[8]; } af[2];
            #pragma unroll
            for (int kk = 0; kk < 2; ++kk)
                #pragma unroll
                for (int j = 0; j < 8; ++j)
                    af[kk].u[j] = f2bu(y[(size_t)(kk*32 + loct*8 + j)*S2 + s0 + lcol]);
            #pragma unroll
            for (int og = 0; og < 4; ++og) {
                int o = og*16 + lcol;
                union { short8 v; unsigned short u[8]; } wfr[2];
                #pragma unroll
                for (int kk = 0; kk < 2; ++kk) {
                    float4 a  = *reinterpret_cast<const float4*>(&wf[o*CIN2 + kk*32 + loct*8]);
                    float4 bq = *reinterpret_cast<const float4*>(&wf[o*CIN2 + kk*32 + loct*8 + 4]);
                    wfr[kk].u[0]=f2bu(a.x);  wfr[kk].u[1]=f2bu(a.y);
                    wfr[kk].u[2]=f2bu(a.z);  wfr[kk].u[3]=f2bu(a.w);
                    wfr[kk].u[4]=f2bu(bq.x); wfr[kk].u[5]=f2bu(bq.y);
                    wfr[kk].u[6]=f2bu(bq.z); wfr[kk].u[7]=f2bu(bq.w);
                }
                float bo = bf[o];
                f32x4 d = { bo, bo, bo, bo };
                d = __builtin_amdgcn_mfma_f32_16x16x32_bf16(af[0].v, wfr[0].v, d, 0, 0, 0);
                d = __builtin_amdgcn_mfma_f32_16x16x32_bf16(af[1].v, wfr[1].v, d, 0, 0, 0);
                ushort4 r4 = { f2bu(d[0]), f2bu(d[1]), f2bu(d[2]), f2bu(d[3]) };
                *reinterpret_cast<ushort4*>(&ot[(og*16 + lcol)*YSTR + wv*16 + loct*4]) = r4;
            }
        }
        __syncthreads();
        #pragma unroll
        for (int j = 0; j < 4; ++j) {
            int row = wv*16 + j*4 + (l >> 4);
            int c4  = l & 15;
            int s   = sblk0 + c4*4;
            if (s < S2) {
                ushort4 v = *reinterpret_cast<const ushort4*>(&ot[row*YSTR + c4*4]);
                *reinterpret_cast<ushort4*>(&yk[(size_t)row*S2 + s]) = v;
            }
        }
    }
}

// ---- MFMA k_M: per channel, M(96x96) = Uxd_pad(96x288) x Uy_pad^T, bf16 out
__global__ __launch_bounds__(256) void k_M(
    const unsigned short* __restrict__ xd, const unsigned short* __restrict__ yk,
    unsigned short* __restrict__ Mg)
{
    __shared__ __align__(16) unsigned short Al[96*ASTR];
    __shared__ __align__(16) unsigned short Bl[96*ASTR];
    int c = blockIdx.x;
    int t = threadIdx.x;
    int l = t & 63, wv = t >> 6;
    int lcol = l & 15, lhi = l >> 4;
    int wr = wv >> 1, wc = wv & 1;

    for (int idx = t; idx < 15*ASTR; idx += 256) {
        Al[81*ASTR + idx] = 0;
        Bl[81*ASTR + idx] = 0;
    }

    f32x4 acc[3][3];
    #pragma unroll
    for (int a = 0; a < 3; ++a)
        #pragma unroll
        for (int b = 0; b < 3; ++b)
            acc[a][b] = (f32x4){0.f,0.f,0.f,0.f};

    const unsigned short* xc = xd + (size_t)c*S2;
    const unsigned short* yc = yk + (size_t)c*S2;

    for (int q = 0; q < 3; ++q) {
        __syncthreads();
        for (int idx = t; idx < 1944; idx += 256) {
            int r18 = idx / 108, u4 = idx - r18*108;
            int srcoff = r18*W2 + q*432 + u4*4;
            ushort4 va = *reinterpret_cast<const ushort4*>(xc + srcoff);
            ushort4 vb = *reinterpret_cast<const ushort4*>(yc + srcoff);
            int ph2 = r18 / 9, i2 = r18 - ph2*9;
            unsigned short ua[4] = {va.x, va.y, va.z, va.w};
            unsigned short ub[4] = {vb.x, vb.y, vb.z, vb.w};
            #pragma unroll
            for (int j = 0; j < 4; ++j) {
                int cc  = u4*4 + j;
                int pw2 = cc / 9, j2 = cc - pw2*9;
                int row = i2*9 + j2;
                int mp  = pw2*2 + ph2;
                Al[row*ASTR + mp] = ua[j];
                Bl[row*ASTR + mp] = ub[j];
            }
        }
        __syncthreads();
        #pragma unroll
        for (int kk = 0; kk < 3; ++kk) {
            short8 afr[3], bfr[3];
            #pragma unroll
            for (int a = 0; a < 3; ++a)
                afr[a] = *reinterpret_cast<const short8*>(
                    &Al[(wr*48 + a*16 + lcol)*ASTR + kk*32 + lhi*8]);
            #pragma unroll
            for (int b = 0; b < 3; ++b)
                bfr[b] = *reinterpret_cast<const short8*>(
                    &Bl[(wc*48 + b*16 + lcol)*ASTR + kk*32 + lhi*8]);
            #pragma unroll
            for (int a = 0; a < 3; ++a)
                #pragma unroll
                for (int b = 0; b < 3; ++b)
                    acc[a][b] = __builtin_amdgcn_mfma_f32_16x16x32_bf16(
                        afr[a], bfr[b], acc[a][b], 0, 0, 0);
        }
    }
    unsigned short* Mc = Mg + (size_t)c*9216;
    #pragma unroll
    for (int a = 0; a < 3; ++a)
        #pragma unroll
        for (int b = 0; b < 3; ++b)
            #pragma unroll
            for (int rr = 0; rr < 4; ++rr) {
                int k1 = wr*48 + a*16 + lhi*4 + rr;
                int k2 = wc*48 + b*16 + lcol;
                Mc[k1*96 + k2] = f2bu(acc[a][b][rr]);
            }
}

// ---- MFMA corr: per (channel, 192-patch chunk): C(96x192) = Mg(96x96,bf16) x Uxq^T
// grid = 64c * 4ph * 3ck = 768 blocks, 256 threads (4 waves); 39936B LDS -> 4 blocks/CU
__global__ __launch_bounds__(256, 4) void k_corr(
    const unsigned short* __restrict__ Mg, const bf16* __restrict__ xq,
    const in_t* __restrict__ z, out_t* __restrict__ out)
{
    __shared__ __align__(16) unsigned short Pl[192*BSTR];   // 39936 B
    int bid = blockIdx.x;
    int c   = bid / 12;
    int rem = bid - c*12;
    int ph  = rem / 3;
    int ck  = rem - ph*3;
    int colbase = ck*1728;
    int t = threadIdx.x;

    for (int idx = t; idx < 192*15; idx += 256) {
        int r = idx/15;
        Pl[r*BSTR + 81 + (idx - r*15)] = 0;
    }
    const unsigned short* xqu =
        (const unsigned short*)(xq + (size_t)c*S1 + (size_t)(ph*9)*W1 + colbase);
    for (int idx = t; idx < 3888; idx += 256) {
        int i2 = idx / 432, v4 = idx - i2*432;
        ushort4 vv = *reinterpret_cast<const ushort4*>(xqu + (size_t)i2*W1 + v4*4);
        int col = v4*4;
        unsigned short uu[4] = {vv.x, vv.y, vv.z, vv.w};
        #pragma unroll
        for (int j = 0; j < 4; ++j) {
            int cc = col + j;
            int p = cc/9, j2 = cc - p*9;
            Pl[p*BSTR + i2*9 + j2] = uu[j];
        }
    }
    __syncthreads();

    int wv = t >> 6, l = t & 63;
    int lrow = l & 15, lhi = l >> 4;

    short8 bfr[3][3];
    #pragma unroll
    for (int ntl = 0; ntl < 3; ++ntl) {
        int n = (wv*3 + ntl)*16 + lrow;
        #pragma unroll
        for (int kk = 0; kk < 3; ++kk)
            bfr[ntl][kk] = *reinterpret_cast<const short8*>(&Pl[n*BSTR + kk*32 + lhi*8]);
    }

    f32x4 acc[6][3];
    #pragma unroll
    for (int mt = 0; mt < 6; ++mt)
        #pragma unroll
        for (int ntl = 0; ntl < 3; ++ntl)
            acc[mt][ntl] = (f32x4){0.f,0.f,0.f,0.f};

    const unsigned short* Mc = Mg + c*9216;
    #pragma unroll
    for (int mt = 0; mt < 6; ++mt) {
        short8 afr[3];
        #pragma unroll
        for (int kk = 0; kk < 3; ++kk)
            afr[kk] = *reinterpret_cast<const short8*>(Mc + (mt*16 + lrow)*96 + kk*32 + lhi*8);
        #pragma unroll
        for (int ntl = 0; ntl < 3; ++ntl) {
            f32x4 d = acc[mt][ntl];
            #pragma unroll
            for (int kk = 0; kk < 3; ++kk)
                d = __builtin_amdgcn_mfma_f32_16x16x32_bf16(afr[kk], bfr[ntl][kk], d, 0, 0, 0);
            acc[mt][ntl] = d;
        }
    }
    __syncthreads();

    float* stage = reinterpret_cast<float*>(Pl);
    #pragma unroll
    for (int pass = 0; pass < 2; ++pass) {
        if ((wv >> 1) == pass) {
            #pragma unroll
            for (int mt = 0; mt < 6; ++mt)
                #pragma unroll
                for (int ntl = 0; ntl < 3; ++ntl) {
                    int n = (wv*3 + ntl)*16 + lrow - pass*96;
                    #pragma unroll
                    for (int r = 0; r < 4; ++r) {
                        int m = mt*16 + lhi*4 + r;
                        if (m <= 80) {
                            int i = m/9, j = m - 9*i;
                            stage[i*864 + n*9 + j] = acc[mt][ntl][r];
                        }
                    }
                }
        }
        __syncthreads();
        for (int idx = t; idx < 1944; idx += 256) {
            int i = idx/216, c4 = idx - i*216;
            float4 sv = *reinterpret_cast<const float4*>(&stage[i*864 + c4*4]);
            int ga = c*S1 + (ph*9 + i)*W1 + colbase + pass*864 + c4*4;
            float4 dv = *reinterpret_cast<const float4*>(&z[ga]);
            float4 ov;
            float cr;
            cr = sv.x*INV_NZ; ov.x = dv.x + (cr > 0.f ? cr : 0.2f*cr)*dv.x;
            cr = sv.y*INV_NZ; ov.y = dv.y + (cr > 0.f ? cr : 0.2f*cr)*dv.y;
            cr = sv.z*INV_NZ; ov.z = dv.z + (cr > 0.f ? cr : 0.2f*cr)*dv.z;
            cr = sv.w*INV_NZ; ov.w = dv.w + (cr > 0.f ? cr : 0.2f*cr)*dv.w;
            *reinterpret_cast<float4*>(&out[ga]) = ov;
        }
        __syncthreads();
    }
}

extern "C" void kernel_launch(void* const* d_in, const int* in_sizes, int n_in,
                              void* d_out, int out_size, void* d_ws, size_t ws_size,
                              hipStream_t stream)
{
    (void)in_sizes; (void)n_in; (void)out_size; (void)ws_size;
    const in_t* x     = (const in_t*)d_in[0];
    const in_t* y     = (const in_t*)d_in[1];
    const in_t* z     = (const in_t*)d_in[2];
    const in_t* w_img = (const in_t*)d_in[3];
    const in_t* b_img = (const in_t*)d_in[4];
    const in_t* w_fea = (const in_t*)d_in[5];
    const in_t* b_fea = (const in_t*)d_in[6];
    out_t* out = (out_t*)d_out;

    char* ws = (char*)d_ws;
    bf16*           xq = (bf16*)          (ws + 0);          // 23,887,872
    unsigned short* yk = (unsigned short*)(ws + 23887872);   // 2,985,984
    unsigned short* xd = (unsigned short*)(ws + 26873856);   // 2,985,984
    unsigned short* Mg = (unsigned short*)(ws + 29859840);   // 1,179,648

    hipLaunchKernelGGL(k_stage1, dim3(NBT), dim3(256), 0, stream,
                       x, w_img, b_img, xq, y, w_fea, b_fea, yk, z, xd);
    hipLaunchKernelGGL(k_M,      dim3(64),  dim3(256), 0, stream, xd, yk, Mg);
    hipLaunchKernelGGL(k_corr,   dim3(768), dim3(256), 0, stream, Mg, xq, z, out);
}

// Round 22
// 65.726 us; speedup vs baseline: 1.2682x; 1.0077x over previous
//
#include <hip/hip_runtime.h>
#include <hip/hip_bf16.h>

typedef __hip_bfloat16 bf16;
typedef float in_t;
typedef float out_t;
typedef __attribute__((ext_vector_type(8))) short short8;   // 8 bf16 MFMA operand
typedef __attribute__((ext_vector_type(4))) float f32x4;    // MFMA accumulator

#define CH    64
#define CIN1  32
#define CIN2  64
#define S1    186624   // 36*72*72
#define W1    5184     // 72*72
#define S2    23328    // 18*36*36
#define W2    1296     // 36*36
#define BSTR  104      // k_corr patch lds bf16 row stride
#define ASTR  104      // k_M operand lds bf16 row stride (b128-aligned)
#define OSTR  136      // proj_x output tile ushort stride
#define YSTR  68       // proj_y output tile ushort stride
#define HWSTR 76       // pool LDS row stride
#define INV_NZ (1.0f/(288.0f + 1e-5f))

#define NB_PL 2304     // pool blocks (half-planes)
#define NB_PX 1458     // proj_x blocks
#define NB_PY 365      // proj_y blocks (4 wave-tiles each)
#define NBT   (NB_PL + NB_PX + NB_PY)   // 4127
#define NBR   (NBT - NB_PL)             // 1823

static __device__ __forceinline__ unsigned short f2bu(float f) {
    bf16 h = __float2bfloat16(f);
    unsigned short u;
    __builtin_memcpy(&u, &h, 2);
    return u;
}

// ---- fused stage 1, Bresenham-interleaved: pool | proj_x | proj_y mixed across dispatch
__global__ __launch_bounds__(256) void k_stage1(
    const in_t* __restrict__ x, const in_t* __restrict__ wi, const in_t* __restrict__ bi,
    bf16* __restrict__ xq,
    const in_t* __restrict__ y, const in_t* __restrict__ wf, const in_t* __restrict__ bf,
    unsigned short* __restrict__ yk,
    const in_t* __restrict__ z, unsigned short* __restrict__ xd)
{
    __shared__ __align__(16) char smem[17408];
    int t = threadIdx.x;
    long long i = blockIdx.x;

    long long pb = (i*NB_PL)/NBT;
    bool is_pool = ((i+1)*NB_PL)/NBT > pb;
    long long r  = i - pb;
    long long yb = (r*NB_PY)/NBR;
    bool is_py   = !is_pool && (((r+1)*NB_PY)/NBR > yb);

    if (is_pool) {
        int bid = (int)pb;
        float* dsum = reinterpret_cast<float*>(smem);
        int c  = bid / 36;
        int rr = bid - c*36;
        int od = rr >> 1, half = rr & 1;
        int hbase = half ? 35 : 0;
        int nrows = half ? 37 : 36;
        int oh0   = half ? 18 : 0;
        int dlo = od ? 2*od - 1 : 0;
        int nd  = od ? 3 : 2;
        const float* zb = z + ((size_t)c*36 + dlo)*W1;
        for (int ii = t; ii < nrows*18; ii += 256) {
            int rw = ii / 18, q = ii - (ii/18)*18;
            int off = (hbase + rw)*18 + q;
            const float4* p0 = reinterpret_cast<const float4*>(zb);
            float4 a = p0[off], b = p0[1296 + off];
            float4 s;
            if (nd == 3) {
                float4 e = p0[2592 + off];
                s = (float4){ a.x+b.x+e.x, a.y+b.y+e.y, a.z+b.z+e.z, a.w+b.w+e.w };
            } else {
                s = (float4){ a.x+b.x, a.y+b.y, a.z+b.z, a.w+b.w };
            }
            *reinterpret_cast<float4*>(&dsum[rw*HWSTR + q*4]) = s;
        }
        __syncthreads();
        float icd = (nd == 3) ? (1.f/3.f) : 0.5f;
        unsigned short* xdp = xd + (size_t)c*S2 + (size_t)od*W2 + oh0*36;
        for (int idx = t; idx < 648; idx += 256) {
            int ohl = idx / 36, ow = idx - (idx/36)*36;
            int oh = oh0 + ohl;
            int h0 = oh ? 2*oh-1 : 0, h1 = 2*oh+1;
            int w0 = ow ? 2*ow-1 : 0, w1 = 2*ow+1;
            float s = 0.f;
            for (int h = h0; h <= h1; ++h) {
                int lr = h - hbase;
                for (int w = w0; w <= w1; ++w)
                    s += dsum[lr*HWSTR + w];
            }
            float ich = (h1 - h0) == 1 ? 0.5f : (1.f/3.f);
            float icw = (w1 - w0) == 1 ? 0.5f : (1.f/3.f);
            xdp[idx] = f2bu(s * icd * ich * icw);
        }
    } else if (!is_py) {
        // ---- proj_x: xq(64,S1) = Wi(64,32) x x(32,S1) + bi, bf16 out
        int gs0 = (int)(r - yb)*128;
        int l = t & 63, wv = t >> 6;
        int lcol = l & 15, loct = l >> 4;

        ushort4 rr4[2][4];
        #pragma unroll
        for (int mt = 0; mt < 2; ++mt) {
            int scol = gs0 + (wv*2 + mt)*16 + lcol;
            union { short8 v; unsigned short u[8]; } af;
            #pragma unroll
            for (int j = 0; j < 8; ++j)
                af.u[j] = f2bu(x[(size_t)(loct*8 + j)*S1 + scol]);
            #pragma unroll
            for (int og = 0; og < 4; ++og) {
                int o = og*16 + lcol;
                union { short8 v; unsigned short u[8]; } wfr;
                float4 a  = *reinterpret_cast<const float4*>(&wi[o*CIN1 + loct*8]);
                float4 bq = *reinterpret_cast<const float4*>(&wi[o*CIN1 + loct*8 + 4]);
                wfr.u[0]=f2bu(a.x);  wfr.u[1]=f2bu(a.y);
                wfr.u[2]=f2bu(a.z);  wfr.u[3]=f2bu(a.w);
                wfr.u[4]=f2bu(bq.x); wfr.u[5]=f2bu(bq.y);
                wfr.u[6]=f2bu(bq.z); wfr.u[7]=f2bu(bq.w);
                float bo = bi[o];
                f32x4 d = { bo, bo, bo, bo };
                d = __builtin_amdgcn_mfma_f32_16x16x32_bf16(af.v, wfr.v, d, 0, 0, 0);
                rr4[mt][og] = (ushort4){ f2bu(d[0]), f2bu(d[1]), f2bu(d[2]), f2bu(d[3]) };
            }
        }
        unsigned short* ot = reinterpret_cast<unsigned short*>(smem);  // 64 x OSTR
        #pragma unroll
        for (int mt = 0; mt < 2; ++mt)
            #pragma unroll
            for (int og = 0; og < 4; ++og)
                *reinterpret_cast<ushort4*>(
                    &ot[(og*16 + lcol)*OSTR + wv*32 + mt*16 + loct*4]) = rr4[mt][og];
        __syncthreads();
        #pragma unroll
        for (int j = 0; j < 4; ++j) {
            int row = wv*16 + j*4 + (l >> 4);
            int c8  = l & 15;
            uint4 v = *reinterpret_cast<const uint4*>(&ot[row*OSTR + c8*8]);
            *reinterpret_cast<uint4*>(
                (unsigned short*)xq + (size_t)row*S1 + gs0 + c8*8) = v;
        }
    } else {
        // ---- proj_y: yk(64,S2) = Wf(64,64) x y(64,S2) + bf, bf16 out
        int pyb   = (int)yb;
        int sblk0 = pyb*64;
        int wv = t >> 6, l = t & 63;
        int lcol = l & 15, loct = l >> 4;
        int tile = pyb*4 + wv;
        unsigned short* ot = reinterpret_cast<unsigned short*>(smem);   // 64 x YSTR
        if (tile < 1458) {
            int s0 = tile*16;
            union { short8 v; unsigned short u[8]; } af[2];
            #pragma unroll
            for (int kk = 0; kk < 2; ++kk)
                #pragma unroll
                for (int j = 0; j < 8; ++j)
                    af[kk].u[j] = f2bu(y[(size_t)(kk*32 + loct*8 + j)*S2 + s0 + lcol]);
            #pragma unroll
            for (int og = 0; og < 4; ++og) {
                int o = og*16 + lcol;
                union { short8 v; unsigned short u[8]; } wfr[2];
                #pragma unroll
                for (int kk = 0; kk < 2; ++kk) {
                    float4 a  = *reinterpret_cast<const float4*>(&wf[o*CIN2 + kk*32 + loct*8]);
                    float4 bq = *reinterpret_cast<const float4*>(&wf[o*CIN2 + kk*32 + loct*8 + 4]);
                    wfr[kk].u[0]=f2bu(a.x);  wfr[kk].u[1]=f2bu(a.y);
                    wfr[kk].u[2]=f2bu(a.z);  wfr[kk].u[3]=f2bu(a.w);
                    wfr[kk].u[4]=f2bu(bq.x); wfr[kk].u[5]=f2bu(bq.y);
                    wfr[kk].u[6]=f2bu(bq.z); wfr[kk].u[7]=f2bu(bq.w);
                }
                float bo = bf[o];
                f32x4 d = { bo, bo, bo, bo };
                d = __builtin_amdgcn_mfma_f32_16x16x32_bf16(af[0].v, wfr[0].v, d, 0, 0, 0);
                d = __builtin_amdgcn_mfma_f32_16x16x32_bf16(af[1].v, wfr[1].v, d, 0, 0, 0);
                ushort4 r4 = { f2bu(d[0]), f2bu(d[1]), f2bu(d[2]), f2bu(d[3]) };
                *reinterpret_cast<ushort4*>(&ot[(og*16 + lcol)*YSTR + wv*16 + loct*4]) = r4;
            }
        }
        __syncthreads();
        #pragma unroll
        for (int j = 0; j < 4; ++j) {
            int row = wv*16 + j*4 + (l >> 4);
            int c4  = l & 15;
            int s   = sblk0 + c4*4;
            if (s < S2) {
                ushort4 v = *reinterpret_cast<const ushort4*>(&ot[row*YSTR + c4*4]);
                *reinterpret_cast<ushort4*>(&yk[(size_t)row*S2 + s]) = v;
            }
        }
    }
}

// ---- MFMA k_M: per channel, M(96x96) = Uxd_pad(96x288) x Uy_pad^T, bf16 out
__global__ __launch_bounds__(256) void k_M(
    const unsigned short* __restrict__ xd, const unsigned short* __restrict__ yk,
    unsigned short* __restrict__ Mg)
{
    __shared__ __align__(16) unsigned short Al[96*ASTR];
    __shared__ __align__(16) unsigned short Bl[96*ASTR];
    int c = blockIdx.x;
    int t = threadIdx.x;
    int l = t & 63, wv = t >> 6;
    int lcol = l & 15, lhi = l >> 4;
    int wr = wv >> 1, wc = wv & 1;

    for (int idx = t; idx < 15*ASTR; idx += 256) {
        Al[81*ASTR + idx] = 0;
        Bl[81*ASTR + idx] = 0;
    }

    f32x4 acc[3][3];
    #pragma unroll
    for (int a = 0; a < 3; ++a)
        #pragma unroll
        for (int b = 0; b < 3; ++b)
            acc[a][b] = (f32x4){0.f,0.f,0.f,0.f};

    const unsigned short* xc = xd + (size_t)c*S2;
    const unsigned short* yc = yk + (size_t)c*S2;

    for (int q = 0; q < 3; ++q) {
        __syncthreads();
        for (int idx = t; idx < 1944; idx += 256) {
            int r18 = idx / 108, u4 = idx - r18*108;
            int srcoff = r18*W2 + q*432 + u4*4;
            ushort4 va = *reinterpret_cast<const ushort4*>(xc + srcoff);
            ushort4 vb = *reinterpret_cast<const ushort4*>(yc + srcoff);
            int ph2 = r18 / 9, i2 = r18 - ph2*9;
            unsigned short ua[4] = {va.x, va.y, va.z, va.w};
            unsigned short ub[4] = {vb.x, vb.y, vb.z, vb.w};
            #pragma unroll
            for (int j = 0; j < 4; ++j) {
                int cc  = u4*4 + j;
                int pw2 = cc / 9, j2 = cc - pw2*9;
                int row = i2*9 + j2;
                int mp  = pw2*2 + ph2;
                Al[row*ASTR + mp] = ua[j];
                Bl[row*ASTR + mp] = ub[j];
            }
        }
        __syncthreads();
        #pragma unroll
        for (int kk = 0; kk < 3; ++kk) {
            short8 afr[3], bfr[3];
            #pragma unroll
            for (int a = 0; a < 3; ++a)
                afr[a] = *reinterpret_cast<const short8*>(
                    &Al[(wr*48 + a*16 + lcol)*ASTR + kk*32 + lhi*8]);
            #pragma unroll
            for (int b = 0; b < 3; ++b)
                bfr[b] = *reinterpret_cast<const short8*>(
                    &Bl[(wc*48 + b*16 + lcol)*ASTR + kk*32 + lhi*8]);
            #pragma unroll
            for (int a = 0; a < 3; ++a)
                #pragma unroll
                for (int b = 0; b < 3; ++b)
                    acc[a][b] = __builtin_amdgcn_mfma_f32_16x16x32_bf16(
                        afr[a], bfr[b], acc[a][b], 0, 0, 0);
        }
    }
    unsigned short* Mc = Mg + (size_t)c*9216;
    #pragma unroll
    for (int a = 0; a < 3; ++a)
        #pragma unroll
        for (int b = 0; b < 3; ++b)
            #pragma unroll
            for (int rr = 0; rr < 4; ++rr) {
                int k1 = wr*48 + a*16 + lhi*4 + rr;
                int k2 = wc*48 + b*16 + lcol;
                Mc[k1*96 + k2] = f2bu(acc[a][b][rr]);
            }
}

// ---- MFMA corr: per (channel, 192-patch chunk): C(96x192) = Mg(96x96,bf16) x Uxq^T
// grid = 768 blocks (XCD-swizzled: each XCD gets 8 whole channels), 256 threads
__global__ __launch_bounds__(256, 4) void k_corr(
    const unsigned short* __restrict__ Mg, const bf16* __restrict__ xq,
    const in_t* __restrict__ z, out_t* __restrict__ out)
{
    __shared__ __align__(16) unsigned short Pl[192*BSTR];   // 39936 B -> 4 blocks/CU
    int bid0 = blockIdx.x;
    // T1 bijective XCD swizzle (768 % 8 == 0): XCD k serves sw in [96k, 96k+96)
    int bid  = (bid0 & 7)*96 + (bid0 >> 3);
    int c   = bid / 12;
    int rem = bid - c*12;
    int ph  = rem / 3;
    int ck  = rem - ph*3;
    int colbase = ck*1728;
    int t = threadIdx.x;

    for (int idx = t; idx < 192*15; idx += 256) {
        int r = idx/15;
        Pl[r*BSTR + 81 + (idx - r*15)] = 0;
    }
    const unsigned short* xqu =
        (const unsigned short*)(xq + (size_t)c*S1 + (size_t)(ph*9)*W1 + colbase);
    for (int idx = t; idx < 3888; idx += 256) {
        int i2 = idx / 432, v4 = idx - i2*432;
        ushort4 vv = *reinterpret_cast<const ushort4*>(xqu + (size_t)i2*W1 + v4*4);
        int col = v4*4;
        unsigned short uu[4] = {vv.x, vv.y, vv.z, vv.w};
        #pragma unroll
        for (int j = 0; j < 4; ++j) {
            int cc = col + j;
            int p = cc/9, j2 = cc - p*9;
            Pl[p*BSTR + i2*9 + j2] = uu[j];
        }
    }
    __syncthreads();

    int wv = t >> 6, l = t & 63;
    int lrow = l & 15, lhi = l >> 4;

    short8 bfr[3][3];
    #pragma unroll
    for (int ntl = 0; ntl < 3; ++ntl) {
        int n = (wv*3 + ntl)*16 + lrow;
        #pragma unroll
        for (int kk = 0; kk < 3; ++kk)
            bfr[ntl][kk] = *reinterpret_cast<const short8*>(&Pl[n*BSTR + kk*32 + lhi*8]);
    }

    f32x4 acc[6][3];
    #pragma unroll
    for (int mt = 0; mt < 6; ++mt)
        #pragma unroll
        for (int ntl = 0; ntl < 3; ++ntl)
            acc[mt][ntl] = (f32x4){0.f,0.f,0.f,0.f};

    const unsigned short* Mc = Mg + c*9216;
    #pragma unroll
    for (int mt = 0; mt < 6; ++mt) {
        short8 afr[3];
        #pragma unroll
        for (int kk = 0; kk < 3; ++kk)
            afr[kk] = *reinterpret_cast<const short8*>(Mc + (mt*16 + lrow)*96 + kk*32 + lhi*8);
        #pragma unroll
        for (int ntl = 0; ntl < 3; ++ntl) {
            f32x4 d = acc[mt][ntl];
            #pragma unroll
            for (int kk = 0; kk < 3; ++kk)
                d = __builtin_amdgcn_mfma_f32_16x16x32_bf16(afr[kk], bfr[ntl][kk], d, 0, 0, 0);
            acc[mt][ntl] = d;
        }
    }
    __syncthreads();

    float* stage = reinterpret_cast<float*>(Pl);
    #pragma unroll
    for (int pass = 0; pass < 2; ++pass) {
        if ((wv >> 1) == pass) {
            #pragma unroll
            for (int mt = 0; mt < 6; ++mt)
                #pragma unroll
                for (int ntl = 0; ntl < 3; ++ntl) {
                    int n = (wv*3 + ntl)*16 + lrow - pass*96;
                    #pragma unroll
                    for (int r = 0; r < 4; ++r) {
                        int m = mt*16 + lhi*4 + r;
                        if (m <= 80) {
                            int i = m/9, j = m - 9*i;
                            stage[i*864 + n*9 + j] = acc[mt][ntl][r];
                        }
                    }
                }
        }
        __syncthreads();
        for (int idx = t; idx < 1944; idx += 256) {
            int i = idx/216, c4 = idx - i*216;
            float4 sv = *reinterpret_cast<const float4*>(&stage[i*864 + c4*4]);
            int ga = c*S1 + (ph*9 + i)*W1 + colbase + pass*864 + c4*4;
            float4 dv = *reinterpret_cast<const float4*>(&z[ga]);
            float4 ov;
            float cr;
            cr = sv.x*INV_NZ; ov.x = dv.x + (cr > 0.f ? cr : 0.2f*cr)*dv.x;
            cr = sv.y*INV_NZ; ov.y = dv.y + (cr > 0.f ? cr : 0.2f*cr)*dv.y;
            cr = sv.z*INV_NZ; ov.z = dv.z + (cr > 0.f ? cr : 0.2f*cr)*dv.z;
            cr = sv.w*INV_NZ; ov.w = dv.w + (cr > 0.f ? cr : 0.2f*cr)*dv.w;
            *reinterpret_cast<float4*>(&out[ga]) = ov;
        }
        __syncthreads();
    }
}

extern "C" void kernel_launch(void* const* d_in, const int* in_sizes, int n_in,
                              void* d_out, int out_size, void* d_ws, size_t ws_size,
                              hipStream_t stream)
{
    (void)in_sizes; (void)n_in; (void)out_size; (void)ws_size;
    const in_t* x     = (const in_t*)d_in[0];
    const in_t* y     = (const in_t*)d_in[1];
    const in_t* z     = (const in_t*)d_in[2];
    const in_t* w_img = (const in_t*)d_in[3];
    const in_t* b_img = (const in_t*)d_in[4];
    const in_t* w_fea = (const in_t*)d_in[5];
    const in_t* b_fea = (const in_t*)d_in[6];
    out_t* out = (out_t*)d_out;

    char* ws = (char*)d_ws;
    bf16*           xq = (bf16*)          (ws + 0);          // 23,887,872
    unsigned short* yk = (unsigned short*)(ws + 23887872);   // 2,985,984
    unsigned short* xd = (unsigned short*)(ws + 26873856);   // 2,985,984
    unsigned short* Mg = (unsigned short*)(ws + 29859840);   // 1,179,648

    hipLaunchKernelGGL(k_stage1, dim3(NBT), dim3(256), 0, stream,
                       x, w_img, b_img, xq, y, w_fea, b_fea, yk, z, xd);
    hipLaunchKernelGGL(k_M,      dim3(64),  dim3(256), 0, stream, xd, yk, Mg);
    hipLaunchKernelGGL(k_corr,   dim3(768), dim3(256), 0, stream, Mg, xq, z, out);
}